// Round 1
// baseline (1931.379 us; speedup 1.0000x reference)
//
#include <hip/hip_runtime.h>
#include <hip/hip_bf16.h>
#include <cmath>

// GMM E-step: N=131072 samples, K=64 components, D=256 features.
// sq[n,k] = ||X P_k - mu_k P_k||^2, wlp = -0.5*sq + C_k, then LSE over k.
// Main engine: bf16 MFMA GEMM, 256x256 tile (BN=256 == D so one block
// owns one full component), BK=64, 8 waves, double-buffered
// global_load_lds staging from pre-swizzled workspace images.

typedef unsigned short ushort_t;
typedef __attribute__((ext_vector_type(4))) float f32x4;
typedef __attribute__((ext_vector_type(8))) short bf16x8;

constexpr int N_ = 131072;
constexpr int K_ = 64;
constexpr int D_ = 256;
constexpr int BM = 256;
constexpr int BK = 64;
constexpr int ROW_TILES = N_ / BM;  // 512
constexpr int NSTEP = D_ / BK;      // 4

// ---------- helpers ----------
__device__ __forceinline__ ushort_t f2bf(float v) {
  unsigned u = __float_as_uint(v);
  u += 0x7FFFu + ((u >> 16) & 1u);  // RNE
  return (ushort_t)(u >> 16);
}

__device__ __forceinline__ void gld16(const ushort_t* g, ushort_t* l) {
  __builtin_amdgcn_global_load_lds(
      (const __attribute__((address_space(1))) unsigned int*)g,
      (__attribute__((address_space(3))) unsigned int*)l, 16, 0, 0);
}

// ---------- prep: X fp32 -> bf16 tiled+swizzled image ----------
// image element e = ((T*4+s)*256 + r)*64 + iq  holds
//   bf16( X[T*256+r][s*64 + (iq ^ ((r&7)<<3))] )
__global__ void prep_x(const float* __restrict__ X, ushort_t* __restrict__ Xb) {
  for (int e = blockIdx.x * blockDim.x + threadIdx.x; e < N_ * D_;
       e += gridDim.x * blockDim.x) {
    int iq = e & 63;
    int r = (e >> 6) & 255;
    int s = (e >> 14) & 3;
    int T = e >> 16;
    int il = iq ^ ((r & 7) << 3);
    Xb[e] = f2bf(X[(size_t)(T * 256 + r) * D_ + s * 64 + il]);
  }
}

// ---------- prep: P fp32 -> bf16 transposed+swizzled image ----------
// image element e = ((k*4+s)*256 + j)*64 + iq  holds
//   bf16( P[k][s*64 + (iq ^ ((j&7)<<3))][j] )
__global__ void prep_p(const float* __restrict__ P, ushort_t* __restrict__ Pb) {
  for (int e = blockIdx.x * blockDim.x + threadIdx.x; e < K_ * D_ * D_;
       e += gridDim.x * blockDim.x) {
    int iq = e & 63;
    int j = (e >> 6) & 255;
    int s = (e >> 14) & 3;
    int k = e >> 16;
    int il = iq ^ ((j & 7) << 3);
    Pb[e] = f2bf(P[((size_t)k * D_ + s * 64 + il) * D_ + j]);
  }
}

// ---------- prep: t[k][j] = sum_i mu[k][i]*P[k][i][j];  C[k] ----------
__global__ void prep_t(const float* __restrict__ P, const float* __restrict__ mu,
                       const float* __restrict__ w, float* __restrict__ t,
                       float* __restrict__ C) {
  int k = blockIdx.x, j = threadIdx.x;
  const float* Pk = P + (size_t)k * D_ * D_;
  const float* muk = mu + (size_t)k * D_;
  float acc = 0.f;
  for (int i = 0; i < D_; ++i) acc += muk[i] * Pk[(size_t)i * D_ + j];
  t[k * D_ + j] = acc;
  __shared__ float red[D_];
  red[j] = logf(Pk[(size_t)j * D_ + j]);  // diag of prec chol (positive)
  __syncthreads();
  for (int s = 128; s > 0; s >>= 1) {
    if (j < s) red[j] += red[j + s];
    __syncthreads();
  }
  if (j == 0)
    C[k] = red[0] + logf(w[k]) - 0.5f * (float)D_ * logf(2.0f * (float)M_PI);
}

// ---------- main fused GEMM + sq-reduce ----------
__global__ __launch_bounds__(512, 2) void gmm_main(
    const ushort_t* __restrict__ Xb, const ushort_t* __restrict__ Pb,
    const float* __restrict__ tvec, const float* __restrict__ Cvec,
    float* __restrict__ wlp /* [N][K] at d_out+1 */) {
  __shared__ __align__(16) ushort_t Al[2][BM * BK];  // 32 KiB each
  __shared__ __align__(16) ushort_t Bl[2][BM * BK];
  __shared__ float sqred[BM][4];

  const int tid = threadIdx.x;
  const int bid = blockIdx.x;
  // bijective XCD swizzle: nwg=32768 -> each XCD gets a contiguous k-range
  const int swz = (bid & 7) * (32768 / 8) + (bid >> 3);
  const int T = swz & (ROW_TILES - 1);
  const int k = swz >> 9;  // /512

  const int wid = tid >> 6, lane = tid & 63;
  const int wr = wid >> 2, wc = wid & 3;  // wave tile: 128 rows x 64 cols
  const int lc = lane & 15, lg = lane >> 4;
  const int swzl = (lc & 7) << 3;  // per-lane LDS XOR swizzle (ushort units)

  const ushort_t* Asrc = Xb + (size_t)T * (BM * D_);
  const ushort_t* Bsrc = Pb + (size_t)k * (BM * D_);

  f32x4 acc[8][4];
#pragma unroll
  for (int m = 0; m < 8; ++m)
#pragma unroll
    for (int n = 0; n < 4; ++n) acc[m][n] = (f32x4){0.f, 0.f, 0.f, 0.f};

  auto STAGE = [&](int b, int s) {
    const ushort_t* ga = Asrc + s * (BM * BK);
    const ushort_t* gb = Bsrc + s * (BM * BK);
#pragma unroll
    for (int it = 0; it < 4; ++it) {
      int off = (it * 512 + tid) * 8;  // 16B chunks, linear image
      gld16(ga + off, &Al[b][off]);
    }
#pragma unroll
    for (int it = 0; it < 4; ++it) {
      int off = (it * 512 + tid) * 8;
      gld16(gb + off, &Bl[b][off]);
    }
  };

  auto COMPUTE = [&](int b) {
#pragma unroll
    for (int ki = 0; ki < 2; ++ki) {
      const int cidx = (ki * 32 + lg * 8) ^ swzl;
      bf16x8 a[8], bb[4];
#pragma unroll
      for (int m = 0; m < 8; ++m) {
        int R = wr * 128 + m * 16 + lc;
        a[m] = *(const bf16x8*)&Al[b][R * 64 + cidx];
      }
#pragma unroll
      for (int n = 0; n < 4; ++n) {
        int Cj = wc * 64 + n * 16 + lc;
        bb[n] = *(const bf16x8*)&Bl[b][Cj * 64 + cidx];
      }
#pragma unroll
      for (int m = 0; m < 8; ++m)
#pragma unroll
        for (int n = 0; n < 4; ++n)
          acc[m][n] = __builtin_amdgcn_mfma_f32_16x16x32_bf16(a[m], bb[n],
                                                              acc[m][n], 0, 0, 0);
    }
  };

  // 2-phase double-buffered K-loop (4 steps total)
  STAGE(0, 0);
  asm volatile("s_waitcnt vmcnt(0)" ::: "memory");
  __syncthreads();
#pragma unroll
  for (int s = 0; s < NSTEP; ++s) {
    const int b = s & 1;
    if (s < NSTEP - 1) STAGE(b ^ 1, s + 1);
    COMPUTE(b);
    if (s < NSTEP - 1) asm volatile("s_waitcnt vmcnt(0)" ::: "memory");
    __syncthreads();
  }

  // epilogue: sq[row] = sum_j (z - t_kj)^2 ; wlp = -0.5*sq + C_k
  float tv[4];
#pragma unroll
  for (int n = 0; n < 4; ++n) tv[n] = tvec[k * D_ + wc * 64 + n * 16 + lc];
  const float Ck = Cvec[k];

#pragma unroll
  for (int m = 0; m < 8; ++m) {
#pragma unroll
    for (int r = 0; r < 4; ++r) {
      float sfl = 0.f;
#pragma unroll
      for (int n = 0; n < 4; ++n) {
        float d = acc[m][n][r] - tv[n];
        sfl += d * d;
      }
      sfl += __shfl_xor(sfl, 1, 64);
      sfl += __shfl_xor(sfl, 2, 64);
      sfl += __shfl_xor(sfl, 4, 64);
      sfl += __shfl_xor(sfl, 8, 64);
      if (lc == 0) sqred[wr * 128 + m * 16 + lg * 4 + r][wc] = sfl;
    }
  }
  __syncthreads();
  if (tid < BM) {
    float sq = sqred[tid][0] + sqred[tid][1] + sqred[tid][2] + sqred[tid][3];
    wlp[(size_t)(T * BM + tid) * K_ + k] = -0.5f * sq + Ck;
  }
}

// ---------- LSE over k + write log_resp, per-block partial sums ----------
__global__ void lse_k(float* __restrict__ out, float* __restrict__ partial) {
  const int row = blockIdx.x * 256 + threadIdx.x;
  float* w = out + 1 + (size_t)row * K_;
  float v[K_];
  float mx = -1e30f;
#pragma unroll
  for (int j = 0; j < K_; ++j) {
    v[j] = w[j];
    mx = fmaxf(mx, v[j]);
  }
  float ssum = 0.f;
#pragma unroll
  for (int j = 0; j < K_; ++j) ssum += expf(v[j] - mx);
  float l = mx + logf(ssum);
#pragma unroll
  for (int j = 0; j < K_; ++j) w[j] = v[j] - l;
  __shared__ float red[256];
  red[threadIdx.x] = l;
  __syncthreads();
  for (int s = 128; s > 0; s >>= 1) {
    if (threadIdx.x < s) red[threadIdx.x] += red[threadIdx.x + s];
    __syncthreads();
  }
  if (threadIdx.x == 0) partial[blockIdx.x] = red[0];
}

__global__ void final_red(const float* __restrict__ partial,
                          float* __restrict__ out) {
  __shared__ float red[512];
  red[threadIdx.x] = partial[threadIdx.x];
  __syncthreads();
  for (int s = 256; s > 0; s >>= 1) {
    if (threadIdx.x < s) red[threadIdx.x] += red[threadIdx.x + s];
    __syncthreads();
  }
  if (threadIdx.x == 0) out[0] = red[0] * (1.0f / (float)N_);
}

extern "C" void kernel_launch(void* const* d_in, const int* in_sizes, int n_in,
                              void* d_out, int out_size, void* d_ws,
                              size_t ws_size, hipStream_t stream) {
  const float* X = (const float*)d_in[0];
  const float* w = (const float*)d_in[1];
  const float* mu = (const float*)d_in[2];
  const float* P = (const float*)d_in[3];
  float* out = (float*)d_out;
  char* ws = (char*)d_ws;

  // ws layout (bytes)
  ushort_t* Xb = (ushort_t*)ws;                         // 67,108,864
  ushort_t* Pb = (ushort_t*)(ws + 67108864);            // 8,388,608
  float* t = (float*)(ws + 75497472);                   // 65,536
  float* C = (float*)(ws + 75563008);                   // 256
  float* partial = (float*)(ws + 75563264);             // 2,048

  prep_x<<<8192, 256, 0, stream>>>(X, Xb);
  prep_p<<<4096, 256, 0, stream>>>(P, Pb);
  prep_t<<<K_, 256, 0, stream>>>(P, mu, w, t, C);
  gmm_main<<<ROW_TILES * K_, 512, 0, stream>>>(Xb, Pb, t, C, out + 1);
  lse_k<<<N_ / 256, 256, 0, stream>>>(out, partial);
  final_red<<<1, 512, 0, stream>>>(partial, out);
}

// Round 2
// 1721.854 us; speedup vs baseline: 1.1217x; 1.1217x over previous
//
#include <hip/hip_runtime.h>
#include <hip/hip_bf16.h>
#include <cmath>

// GMM E-step: N=131072, K=64, D=256.
// Round 2: A-resident structure. Each block owns 128 rows of X, staged to
// LDS once; loops over all 64 components streaming P_k through a
// double-buffered 32KB LDS buffer (L2-hot). Far-memory traffic ~15x lower
// than round 1's per-(T,k) staging.

typedef unsigned short ushort_t;
typedef __attribute__((ext_vector_type(4))) float f32x4;
typedef __attribute__((ext_vector_type(8))) short bf16x8;

constexpr int N_ = 131072;
constexpr int K_ = 64;
constexpr int D_ = 256;
constexpr int BM = 128;                 // rows per block
constexpr int NBLK = N_ / BM;           // 1024 blocks
constexpr int BK = 64;                  // contraction substep
constexpr int NSTEP = D_ / BK;          // 4 substeps per component

// ---------- helpers ----------
__device__ __forceinline__ ushort_t f2bf(float v) {
  unsigned u = __float_as_uint(v);
  u += 0x7FFFu + ((u >> 16) & 1u);  // RNE
  return (ushort_t)(u >> 16);
}

__device__ __forceinline__ void gld16(const ushort_t* g, ushort_t* l) {
  __builtin_amdgcn_global_load_lds(
      (const __attribute__((address_space(1))) unsigned int*)g,
      (__attribute__((address_space(3))) unsigned int*)l, 16, 0, 0);
}

// ---------- prep: X fp32 -> bf16 tiled+swizzled image (128-row tiles) ----
// image element e = ((T*4+s)*128 + r)*64 + iq  holds
//   bf16( X[T*128+r][s*64 + (iq ^ ((r&7)<<3))] )
__global__ void prep_x(const float* __restrict__ X, ushort_t* __restrict__ Xb) {
  for (int e = blockIdx.x * blockDim.x + threadIdx.x; e < N_ * D_;
       e += gridDim.x * blockDim.x) {
    int iq = e & 63;
    int r = (e >> 6) & 127;
    int s = (e >> 13) & 3;
    int T = e >> 15;
    int il = iq ^ ((r & 7) << 3);
    Xb[e] = f2bf(X[(size_t)(T * 128 + r) * D_ + s * 64 + il]);
  }
}

// ---------- prep: P fp32 -> bf16 transposed+swizzled image ----------
// image element e = ((k*4+s)*256 + j)*64 + iq  holds
//   bf16( P[k][s*64 + (iq ^ ((j&7)<<3))][j] )
__global__ void prep_p(const float* __restrict__ P, ushort_t* __restrict__ Pb) {
  for (int e = blockIdx.x * blockDim.x + threadIdx.x; e < K_ * D_ * D_;
       e += gridDim.x * blockDim.x) {
    int iq = e & 63;
    int j = (e >> 6) & 255;
    int s = (e >> 14) & 3;
    int k = e >> 16;
    int il = iq ^ ((j & 7) << 3);
    Pb[e] = f2bf(P[((size_t)k * D_ + s * 64 + il) * D_ + j]);
  }
}

// ---------- prep: t[k][j] = sum_i mu[k][i]*P[k][i][j];  C[k] ----------
__global__ void prep_t(const float* __restrict__ P, const float* __restrict__ mu,
                       const float* __restrict__ w, float* __restrict__ t,
                       float* __restrict__ C) {
  int k = blockIdx.x, j = threadIdx.x;
  const float* Pk = P + (size_t)k * D_ * D_;
  const float* muk = mu + (size_t)k * D_;
  float acc = 0.f;
  for (int i = 0; i < D_; ++i) acc += muk[i] * Pk[(size_t)i * D_ + j];
  t[k * D_ + j] = acc;
  __shared__ float red[D_];
  red[j] = logf(Pk[(size_t)j * D_ + j]);  // diag of prec chol (positive)
  __syncthreads();
  for (int s = 128; s > 0; s >>= 1) {
    if (j < s) red[j] += red[j + s];
    __syncthreads();
  }
  if (j == 0)
    C[k] = red[0] + logf(w[k]) - 0.5f * (float)D_ * logf(2.0f * (float)M_PI);
}

// ---------- main: A-resident fused GEMM + per-k sq-reduce ----------
__global__ __launch_bounds__(512, 2) void gmm_main(
    const ushort_t* __restrict__ Xb, const ushort_t* __restrict__ Pb,
    const float* __restrict__ tvec, const float* __restrict__ Cvec,
    float* __restrict__ wlp /* [N][K] */) {
  __shared__ __align__(16) ushort_t Al[4 * 128 * 64];   // 64 KiB, X tile
  __shared__ __align__(16) ushort_t Bl[2][256 * 64];    // 64 KiB, P_k dbuf
  __shared__ float sqred[BM][4];

  const int tid = threadIdx.x;
  const int T = blockIdx.x;

  const int wid = tid >> 6, lane = tid & 63;
  const int wr = wid >> 2, wc = wid & 3;  // wave tile: 64 rows x 64 cols
  const int lc = lane & 15, lg = lane >> 4;
  const int swzl = (lc & 7) << 3;  // LDS XOR swizzle (ushort units)

  const ushort_t* Asrc = Xb + (size_t)T * (BM * D_);

  auto STAGE_B = [&](int buf, int step) {
    const ushort_t* gb = Pb + (size_t)step * (256 * 64);
#pragma unroll
    for (int it = 0; it < 4; ++it) {
      int off = (it * 512 + tid) * 8;  // 16B chunks, linear image
      gld16(gb + off, &Bl[buf][off]);
    }
  };

  // stage A once (64 KiB) + first B chunk
#pragma unroll
  for (int it = 0; it < 8; ++it) {
    int off = (it * 512 + tid) * 8;
    gld16(Asrc + off, &Al[off]);
  }
  STAGE_B(0, 0);
  asm volatile("s_waitcnt vmcnt(0)" ::: "memory");
  __syncthreads();

  int b = 0;
#pragma unroll 1
  for (int k = 0; k < K_; ++k) {
    // issue t/C loads early; consumed ~5000 cyc later in the epilogue
    float tv[4];
#pragma unroll
    for (int n = 0; n < 4; ++n) tv[n] = tvec[k * D_ + wc * 64 + n * 16 + lc];
    const float Ck = Cvec[k];

    f32x4 acc[4][4];
#pragma unroll
    for (int m = 0; m < 4; ++m)
#pragma unroll
      for (int n = 0; n < 4; ++n) acc[m][n] = (f32x4){0.f, 0.f, 0.f, 0.f};

#pragma unroll
    for (int s = 0; s < NSTEP; ++s) {
      const int step = k * NSTEP + s;
      if (step < K_ * NSTEP - 1) STAGE_B(b ^ 1, step + 1);
      // compute on Bl[b] against A slice s
      {
        const ushort_t* As = &Al[s * (128 * 64)];
#pragma unroll
        for (int ki = 0; ki < 2; ++ki) {
          const int cidx = (ki * 32 + lg * 8) ^ swzl;
          bf16x8 a[4], bb[4];
#pragma unroll
          for (int m = 0; m < 4; ++m)
            a[m] = *(const bf16x8*)&As[(wr * 64 + m * 16 + lc) * 64 + cidx];
#pragma unroll
          for (int n = 0; n < 4; ++n)
            bb[n] = *(const bf16x8*)&Bl[b][(wc * 64 + n * 16 + lc) * 64 + cidx];
#pragma unroll
          for (int m = 0; m < 4; ++m)
#pragma unroll
            for (int n = 0; n < 4; ++n)
              acc[m][n] = __builtin_amdgcn_mfma_f32_16x16x32_bf16(
                  a[m], bb[n], acc[m][n], 0, 0, 0);
        }
      }
      asm volatile("s_waitcnt vmcnt(0)" ::: "memory");
      __syncthreads();
      b ^= 1;
    }

    // epilogue for component k: sq = sum_j (z - t_j)^2, wave-local + LDS
#pragma unroll
    for (int m = 0; m < 4; ++m) {
#pragma unroll
      for (int r = 0; r < 4; ++r) {
        float sfl = 0.f;
#pragma unroll
        for (int n = 0; n < 4; ++n) {
          float d = acc[m][n][r] - tv[n];
          sfl += d * d;
        }
        sfl += __shfl_xor(sfl, 1, 64);
        sfl += __shfl_xor(sfl, 2, 64);
        sfl += __shfl_xor(sfl, 4, 64);
        sfl += __shfl_xor(sfl, 8, 64);
        if (lc == 0) sqred[wr * 64 + m * 16 + lg * 4 + r][wc] = sfl;
      }
    }
    __syncthreads();
    if (tid < BM) {
      float sq = sqred[tid][0] + sqred[tid][1] + sqred[tid][2] + sqred[tid][3];
      wlp[(size_t)(T * BM + tid) * K_ + k] = -0.5f * sq + Ck;
    }
    // no extra barrier needed: next sqred write is >=4 substep barriers away
  }
}

// ---------- LSE over k + write log_resp, per-block partial sums ----------
__global__ void lse_k(float* __restrict__ out, float* __restrict__ partial) {
  const int row = blockIdx.x * 256 + threadIdx.x;
  float* w = out + 1 + (size_t)row * K_;
  float v[K_];
  float mx = -1e30f;
#pragma unroll
  for (int j = 0; j < K_; ++j) {
    v[j] = w[j];
    mx = fmaxf(mx, v[j]);
  }
  float ssum = 0.f;
#pragma unroll
  for (int j = 0; j < K_; ++j) ssum += expf(v[j] - mx);
  float l = mx + logf(ssum);
#pragma unroll
  for (int j = 0; j < K_; ++j) w[j] = v[j] - l;
  __shared__ float red[256];
  red[threadIdx.x] = l;
  __syncthreads();
  for (int s = 128; s > 0; s >>= 1) {
    if (threadIdx.x < s) red[threadIdx.x] += red[threadIdx.x + s];
    __syncthreads();
  }
  if (threadIdx.x == 0) partial[blockIdx.x] = red[0];
}

__global__ void final_red(const float* __restrict__ partial,
                          float* __restrict__ out) {
  __shared__ float red[512];
  red[threadIdx.x] = partial[threadIdx.x];
  __syncthreads();
  for (int s = 256; s > 0; s >>= 1) {
    if (threadIdx.x < s) red[threadIdx.x] += red[threadIdx.x + s];
    __syncthreads();
  }
  if (threadIdx.x == 0) out[0] = red[0] * (1.0f / (float)N_);
}

extern "C" void kernel_launch(void* const* d_in, const int* in_sizes, int n_in,
                              void* d_out, int out_size, void* d_ws,
                              size_t ws_size, hipStream_t stream) {
  const float* X = (const float*)d_in[0];
  const float* w = (const float*)d_in[1];
  const float* mu = (const float*)d_in[2];
  const float* P = (const float*)d_in[3];
  float* out = (float*)d_out;
  char* ws = (char*)d_ws;

  // ws layout (bytes)
  ushort_t* Xb = (ushort_t*)ws;                         // 67,108,864
  ushort_t* Pb = (ushort_t*)(ws + 67108864);            // 8,388,608
  float* t = (float*)(ws + 75497472);                   // 65,536
  float* C = (float*)(ws + 75563008);                   // 256
  float* partial = (float*)(ws + 75563264);             // 2,048

  prep_x<<<2048, 256, 0, stream>>>(X, Xb);
  prep_p<<<2048, 256, 0, stream>>>(P, Pb);
  prep_t<<<K_, 256, 0, stream>>>(P, mu, w, t, C);
  gmm_main<<<NBLK, 512, 0, stream>>>(Xb, Pb, t, C, out + 1);
  lse_k<<<N_ / 256, 256, 0, stream>>>(out, partial);
  final_red<<<1, 512, 0, stream>>>(partial, out);
}